// Round 8
// baseline (78738.239 us; speedup 1.0000x reference)
//
#include <hip/hip_runtime.h>

// DIAGNOSIS ROUND: localize the 1-spike discrepancy of the phase-decomposed
// kernel (rounds 6/7) against the proven per-step kernel (round 5).
//  - d_out is produced by the PER-STEP path (round-5 verbatim math, which
//    passed with absmax 0.0), fed from phase-A bit-stored layer-1 spikes.
//  - The chunked layer-2 and chunked layer-3 paths (round-7 verbatim) run as
//    shadow computations; mismatches vs the per-step spikes set block flags.
//  - Flags convert to calibrated delay loops => verdict readable from dur_us:
//      base ~4-6ms | +2.5ms: chunked-L2 guilty | +5.8ms: chunked-L3 guilty.

typedef float f32x2 __attribute__((ext_vector_type(2)));
typedef float f32x4 __attribute__((ext_vector_type(4)));

#define B_TOT  8192
#define IN     256
#define H1     512
#define H2     256
#define NOUT   64
#define T_STEPS 50
#define WIN    10
#define BB     8
#define NTHR   512
#define TC     10
#define NCH    5
#define KT     64
#define DELAY_B 1500000   // ~2.5 ms (4-cyc fma dep chain)
#define DELAY_C 3500000   // ~5.8 ms

__device__ __forceinline__ void pk_fma(f32x2& acc, f32x2 a, f32x2 b) {
    asm("v_pk_fma_f32 %0, %1, %2, %0" : "+v"(acc) : "v"(a), "v"(b));
}
__device__ __forceinline__ float lif_v(float V, float I) {
    return __fadd_rn(__fmul_rn(0.9f, V), I);   // two separately-rounded ops
}

__global__ __launch_bounds__(NTHR, 4)
void snn_diag(const float* __restrict__ x,
              const float* __restrict__ W1, const float* __restrict__ b1,
              const float* __restrict__ W2, const float* __restrict__ b2,
              const float* __restrict__ W3, const float* __restrict__ b3,
              float* __restrict__ out, float* __restrict__ ws)
{
    __shared__ __align__(16) float Arena[6144];       // 24576 B multi-use
    __shared__ unsigned char S1b[T_STEPS][H1];        // 25600 B: L1 spike bits
    __shared__ unsigned char S2bc[T_STEPS][H2][2];    // 25600 B: chunked-L2 bits
    __shared__ int flagB, flagC;

    const int t  = threadIdx.x;
    const int b0 = blockIdx.x * BB;
    if (t == 0) { flagB = 0; flagC = 0; }

    const int jj = t & (H2 - 1);
    const int g4 = (t >> 8) * 4;
    const int o    = t & (NOUT - 1);
    const int brow = t >> 6;
    const float b2v = b2[jj];
    const float b3v = b3[o];
    const float* w2c = W2 + jj;
    const float* w3c = W3 + o;

    // ================= phase A: layer 1 bits (round-7 verbatim) =============
    {
        float* xs = Arena;
        for (int i = t; i < BB * IN; i += NTHR) xs[i] = x[(size_t)b0 * IN + i];
        __syncthreads();
        float I1r[BB];
        #pragma unroll
        for (int b = 0; b < BB; b++) I1r[b] = 0.0f;
        for (int k = 0; k < IN; k++) {
            float w = W1[k * H1 + t];
            #pragma unroll
            for (int b = 0; b < BB; b++)
                I1r[b] = __fmaf_rn(xs[b * IN + k], w, I1r[b]);
        }
        float bb = b1[t];
        #pragma unroll
        for (int b = 0; b < BB; b++) I1r[b] = __fadd_rn(I1r[b], bb);

        float V1[BB];
        #pragma unroll
        for (int b = 0; b < BB; b++) V1[b] = 0.0f;
        unsigned r1 = 0;
        for (int st = 0; st < T_STEPS; st++) {
            unsigned m = 0;
            #pragma unroll
            for (int b = 0; b < BB; b++) {
                float V = lif_v(V1[b], I1r[b]);
                bool act = (V >= 1.0f) & !((r1 >> b) & 1u);
                V1[b] = act ? 0.0f : V;
                m |= (unsigned)act << b;
            }
            r1 = m;
            S1b[st][t] = (unsigned char)m;
        }
    }
    __syncthreads();

    // ============ phase 2: SHADOW chunked layer-2 (round-7 verbatim) ========
    {
        float V2c[4] = {0.f, 0.f, 0.f, 0.f};
        unsigned r2c = 0;
        float (*SfB)[TC][8] = (float (*)[TC][8])Arena;
        for (int c = 0; c < NCH; c++) {
            const int t0 = c * TC;
            f32x4 acc[TC];
            #pragma unroll
            for (int i = 0; i < TC; i++) acc[i] = (f32x4){0.f, 0.f, 0.f, 0.f};
            for (int kt = 0; kt < H1 / KT; kt++) {
                const int k0 = kt * KT;
                __syncthreads();
                for (int cell = t; cell < KT * TC; cell += NTHR) {
                    const int kk = cell / TC;
                    const int st = cell - kk * TC;
                    const unsigned m = S1b[t0 + st][k0 + kk];
                    f32x4 lo, hi;
                    #pragma unroll
                    for (int i = 0; i < 4; i++) lo[i] = (float)((m >> i) & 1u);
                    #pragma unroll
                    for (int i = 0; i < 4; i++) hi[i] = (float)((m >> (4 + i)) & 1u);
                    f32x4* dst = (f32x4*)&SfB[kk][st][0];
                    dst[0] = lo;
                    dst[1] = hi;
                }
                __syncthreads();
                const float* wp = w2c + (size_t)k0 * H2;
                #pragma unroll 2
                for (int k = 0; k < KT; k++) {
                    const float w = wp[(size_t)k * H2];
                    const f32x4 wv = {w, w, w, w};
                    #pragma unroll
                    for (int tt = 0; tt < TC; tt++) {
                        f32x4 s = *(const f32x4*)&SfB[k][tt][g4];
                        acc[tt] = wv * s + acc[tt];
                    }
                }
            }
            #pragma unroll
            for (int tt = 0; tt < TC; tt++) {
                unsigned m = 0;
                #pragma unroll
                for (int i = 0; i < 4; i++) {
                    float I2 = __fadd_rn(acc[tt][i], b2v);
                    float V = lif_v(V2c[i], I2);
                    bool act = (V >= 1.0f) & !((r2c >> i) & 1u);
                    V2c[i] = act ? 0.0f : V;
                    m |= (unsigned)act << i;
                }
                r2c = m;
                S2bc[t0 + tt][jj][g4 >> 2] = (unsigned char)m;
            }
        }
    }
    __syncthreads();

    // ====== phase 3: AUTHORITATIVE per-step layers 2+3 (round-5 verbatim) ===
    unsigned mmB = 0, mmC = 0;
    unsigned csp0 = 0, csp1 = 0;    // per-step layer-3 spike train
    int cnt = 0;
    {
        float* S1f = Arena;          // [512][8] floats
        float* S2f = Arena + 4096;   // [256][8] floats
        float V2p[4] = {0.f, 0.f, 0.f, 0.f};
        unsigned r2p = 0;
        float V3p = 0.0f;
        unsigned r3p = 0;
        for (int st = 0; st < T_STEPS; st++) {
            {   // expand layer-1 bits -> floats (thread t owns h1 = t)
                unsigned m = S1b[st][t];
                f32x4 lo, hi;
                #pragma unroll
                for (int i = 0; i < 4; i++) lo[i] = (float)((m >> i) & 1u);
                #pragma unroll
                for (int i = 0; i < 4; i++) hi[i] = (float)((m >> (4 + i)) & 1u);
                f32x4* dst = (f32x4*)(S1f + t * BB);
                dst[0] = lo;
                dst[1] = hi;
            }
            __syncthreads();   // (A)

            f32x2 accA = {0.f, 0.f}, accB = {0.f, 0.f};
            const float* srow = S1f + g4;
            #pragma unroll 4
            for (int k = 0; k < H1; k++) {
                float w = w2c[(size_t)k * H2];
                f32x2 wsv = {w, w};
                f32x4 s = *(const f32x4*)(srow + k * BB);
                pk_fma(accA, wsv, __builtin_shufflevector(s, s, 0, 1));
                pk_fma(accB, wsv, __builtin_shufflevector(s, s, 2, 3));
            }
            float sf2[4];
            unsigned bits2 = 0;
            #pragma unroll
            for (int i = 0; i < 4; i++) {
                float ai = (i < 2) ? accA[i] : accB[i - 2];
                float I2 = __fadd_rn(ai, b2v);
                float V = lif_v(V2p[i], I2);
                bool act = (V >= 1.0f) & !((r2p >> i) & 1u);
                V2p[i] = act ? 0.0f : V;
                sf2[i] = act ? 1.0f : 0.0f;
                bits2 |= (unsigned)act << i;
            }
            r2p = bits2;
            mmB |= bits2 ^ (unsigned)S2bc[st][jj][g4 >> 2];   // L2 compare
            *(f32x4*)(S2f + jj * BB + g4) = (f32x4){sf2[0], sf2[1], sf2[2], sf2[3]};
            __syncthreads();   // (B)

            float a3 = 0.0f;
            const float* s2r = S2f + brow;
            #pragma unroll 4
            for (int k = 0; k < H2; k++)
                a3 = __fmaf_rn(w3c[(size_t)k * NOUT], s2r[k * BB], a3);
            {
                float I3 = __fadd_rn(a3, b3v);
                float V = lif_v(V3p, I3);
                bool act = (V >= 1.0f) & !(r3p & 1u);
                V3p = act ? 0.0f : V;
                r3p = (unsigned)act;
                if (st < 32) csp0 |= (unsigned)act << st;
                else         csp1 |= (unsigned)act << (st - 32);
                if (st >= T_STEPS - WIN) cnt += (int)act;
            }
        }
        out[(size_t)(b0 + brow) * NOUT + o] = (float)cnt / 10.0f;   // authoritative
    }
    __syncthreads();

    // ============ phase 4: SHADOW chunked layer-3 (round-7 verbatim) ========
    {
        float V3c = 0.0f;
        unsigned r3c = 0;
        int cntc = 0;
        float (*SfC)[8][12] = (float (*)[8][12])Arena;
        for (int c = 0; c < NCH; c++) {
            const int t0 = c * TC;
            f32x4 aA = {0.f,0.f,0.f,0.f}, aB = {0.f,0.f,0.f,0.f};
            f32x2 aC = {0.f, 0.f};
            for (int kt = 0; kt < H2 / KT; kt++) {
                const int k0 = kt * KT;
                __syncthreads();
                for (int cell = t; cell < KT * 8; cell += NTHR) {
                    const int kk = cell >> 3;
                    const int rr = cell & 7;
                    float f[TC];
                    #pragma unroll
                    for (int j = 0; j < TC; j++)
                        f[j] = (float)((S2bc[t0 + j][k0 + kk][rr >> 2] >> (rr & 3)) & 1u);
                    float* dst = &SfC[kk][rr][0];
                    ((f32x4*)dst)[0] = (f32x4){f[0], f[1], f[2], f[3]};
                    ((f32x4*)dst)[1] = (f32x4){f[4], f[5], f[6], f[7]};
                    *(f32x2*)(dst + 8) = (f32x2){f[8], f[9]};
                }
                __syncthreads();
                const float* wp = w3c + (size_t)k0 * NOUT;
                #pragma unroll 2
                for (int k = 0; k < KT; k++) {
                    const float w = wp[(size_t)k * NOUT];
                    const float* sp = &SfC[k][brow][0];
                    f32x4 sA = *(const f32x4*)sp;
                    f32x4 sB = *(const f32x4*)(sp + 4);
                    f32x2 sC = *(const f32x2*)(sp + 8);
                    aA = (f32x4){w,w,w,w} * sA + aA;
                    aB = (f32x4){w,w,w,w} * sB + aB;
                    aC = (f32x2){w,w} * sC + aC;
                }
            }
            #pragma unroll
            for (int tt = 0; tt < TC; tt++) {
                float av = (tt < 4) ? aA[tt] : (tt < 8) ? aB[tt - 4] : aC[tt - 8];
                float I3 = __fadd_rn(av, b3v);
                float V = lif_v(V3c, I3);
                bool act = (V >= 1.0f) & !(r3c & 1u);
                V3c = act ? 0.0f : V;
                r3c = (unsigned)act;
                const int stg = t0 + tt;
                unsigned ps = (stg < 32) ? (csp0 >> stg) : (csp1 >> (stg - 32));
                mmC |= (unsigned)act ^ (ps & 1u);             // L3 compare
                if (stg >= T_STEPS - WIN) cntc += (int)act;
            }
        }
        mmC |= (unsigned)(cntc != cnt);
    }

    // ================= phase 5: verdict -> timing side-channel ==============
    if (mmB) atomicOr(&flagB, 1);
    if (mmC) atomicOr(&flagC, 1);
    __syncthreads();
    const int nIter = flagB * DELAY_B + flagC * DELAY_C;
    float d = 1.0f + (float)t * 1e-7f;
    for (int i = 0; i < nIter; i++) d = __fmaf_rn(d, 0.9999999f, 1e-9f);
    if (d == 123.456789f) ws[t] = d;   // never taken; keeps the chain live
}

extern "C" void kernel_launch(void* const* d_in, const int* in_sizes, int n_in,
                              void* d_out, int out_size, void* d_ws, size_t ws_size,
                              hipStream_t stream)
{
    const float* x  = (const float*)d_in[0];
    const float* W1 = (const float*)d_in[1];
    const float* b1 = (const float*)d_in[2];
    const float* W2 = (const float*)d_in[3];
    const float* b2 = (const float*)d_in[4];
    const float* W3 = (const float*)d_in[5];
    const float* b3 = (const float*)d_in[6];
    float* out = (float*)d_out;

    dim3 grid(B_TOT / BB);   // 1024 blocks
    dim3 block(NTHR);        // 512 threads
    hipLaunchKernelGGL(snn_diag, grid, block, 0, stream,
                       x, W1, b1, W2, b2, W3, b3, out, (float*)d_ws);
}